// Round 11
// baseline (247.193 us; speedup 1.0000x reference)
//
#include <hip/hip_runtime.h>
#include <hip/hip_bf16.h>

#define NN 8192
#define NFEAT 512
#define NHID 64
#define NCLASS 16
#define NHEAD 4
#define ALPHA 0.1f
#define CAP 768   // max neighbors per row (expected 410 +- 20; 18 sigma)

typedef short bf16x8 __attribute__((ext_vector_type(8)));
typedef float f32x4 __attribute__((ext_vector_type(4)));
typedef float fv4 __attribute__((ext_vector_type(4)));   // clang-native for nontemporal

__device__ __forceinline__ float lrelu(float x) { return fmaxf(x, ALPHA * x); }
__device__ __forceinline__ float elu(float x) { return x > 0.f ? x : __expf(x) - 1.f; }
__device__ __forceinline__ short f2b(float x) {
  union { __bf16 b; short s; } c; c.b = (__bf16)x; return c.s;
}
__device__ __forceinline__ float b2f(short x) {
  union { unsigned int u; float f; } c; c.u = ((unsigned int)(unsigned short)x) << 16; return c.f;
}

// unpack a packed bf16 pair (one dword) and FMA into two accumulators
#define UPF(w, v, A0, A1)                                  \
  {                                                        \
    const float lo_ = __uint_as_float((v) << 16);          \
    const float hi_ = __uint_as_float((v) & 0xffff0000u);  \
    (A0) += (w) * lo_;                                     \
    (A1) += (w) * hi_;                                     \
  }

// ---------------- K0b: WB[h][d][k] = bf16(W[h][k][d]) ----------------
__global__ __launch_bounds__(256) void k_wprep(const float* __restrict__ W,
                                               short* __restrict__ WB) {
  __shared__ float t[64][65];
  const int h = blockIdx.y;
  const int k0 = blockIdx.x * 64;
  const int tid = threadIdx.x;
#pragma unroll
  for (int it = 0; it < 16; ++it) {
    const int r = it * 4 + (tid >> 6), c = tid & 63;
    t[r][c] = W[((size_t)h * NFEAT + k0 + r) * NHID + c];
  }
  __syncthreads();
#pragma unroll
  for (int it = 0; it < 16; ++it) {
    const int d = it * 4 + (tid >> 6), k = tid & 63;
    WB[((size_t)h * NHID + d) * NFEAT + k0 + k] = f2b(t[k][d]);
  }
}

// ---------------- K1: Wh = bf16(x) @ WB^T (MFMA); epilogue f1/f2 + WhB2 tables ----------
// WhB2: two head-pair tables, each [NN][128] bf16 (2 MB) — table p holds heads 2p, 2p+1.
__global__ __launch_bounds__(256) void k_prep1(const float* __restrict__ x,
                                               const short* __restrict__ WB,
                                               const float* __restrict__ a,
                                               short* __restrict__ WhB2,
                                               float* __restrict__ f1i,
                                               float* __restrict__ f2i) {
  __shared__ short tile[64][72];
  const int bid = blockIdx.x;
  const int h = bid >> 7;
  const int bm = (bid & 127) * 64;
  const int tid = threadIdx.x;
  const int wv = tid >> 6, lane = tid & 63;
  const int mr = lane & 15, kg = lane >> 4;
  f32x4 acc0 = {0.f, 0.f, 0.f, 0.f}, acc1 = acc0, acc2 = acc0, acc3 = acc0;
  const float* ap = x + (size_t)(bm + wv * 16 + mr) * NFEAT + kg * 8;
  const short* bp = WB + ((size_t)h * NHID + mr) * NFEAT + kg * 8;
#pragma unroll 2
  for (int k0 = 0; k0 < NFEAT; k0 += 32) {
    const float4 xa = *reinterpret_cast<const float4*>(ap);
    const float4 xb = *reinterpret_cast<const float4*>(ap + 4);
    bf16x8 af;
    af[0] = f2b(xa.x); af[1] = f2b(xa.y); af[2] = f2b(xa.z); af[3] = f2b(xa.w);
    af[4] = f2b(xb.x); af[5] = f2b(xb.y); af[6] = f2b(xb.z); af[7] = f2b(xb.w);
    const bf16x8 b0 = *reinterpret_cast<const bf16x8*>(bp);
    const bf16x8 b1 = *reinterpret_cast<const bf16x8*>(bp + 16 * NFEAT);
    const bf16x8 b2 = *reinterpret_cast<const bf16x8*>(bp + 32 * NFEAT);
    const bf16x8 b3 = *reinterpret_cast<const bf16x8*>(bp + 48 * NFEAT);
    acc0 = __builtin_amdgcn_mfma_f32_16x16x32_bf16(af, b0, acc0, 0, 0, 0);
    acc1 = __builtin_amdgcn_mfma_f32_16x16x32_bf16(af, b1, acc1, 0, 0, 0);
    acc2 = __builtin_amdgcn_mfma_f32_16x16x32_bf16(af, b2, acc2, 0, 0, 0);
    acc3 = __builtin_amdgcn_mfma_f32_16x16x32_bf16(af, b3, acc3, 0, 0, 0);
    ap += 32; bp += 32;
  }
  float a1v[4], a2v[4];
#pragma unroll
  for (int c = 0; c < 4; ++c) {
    a1v[c] = a[h * 128 + mr + c * 16];
    a2v[c] = a[h * 128 + 64 + mr + c * 16];
  }
#pragma unroll
  for (int q = 0; q < 4; ++q) {
    float s1 = acc0[q] * a1v[0] + acc1[q] * a1v[1] + acc2[q] * a1v[2] + acc3[q] * a1v[3];
    float s2 = acc0[q] * a2v[0] + acc1[q] * a2v[1] + acc2[q] * a2v[2] + acc3[q] * a2v[3];
#pragma unroll
    for (int off = 1; off < 16; off <<= 1) {
      s1 += __shfl_xor(s1, off);
      s2 += __shfl_xor(s2, off);
    }
    if (mr == 0) {
      const int i = bm + wv * 16 + kg * 4 + q;
      f1i[(size_t)i * 4 + h] = s1;
      f2i[(size_t)i * 4 + h] = s2;
    }
  }
#pragma unroll
  for (int q = 0; q < 4; ++q) {
    const int r = wv * 16 + kg * 4 + q;
    tile[r][mr +  0] = f2b(acc0[q]);
    tile[r][mr + 16] = f2b(acc1[q]);
    tile[r][mr + 32] = f2b(acc2[q]);
    tile[r][mr + 48] = f2b(acc3[q]);
  }
  __syncthreads();
  {
    const int row = tid >> 2, seg = tid & 3;
    bf16x8 o0, o1;
#pragma unroll
    for (int u = 0; u < 8; ++u) {
      o0[u] = tile[row][seg * 16 + u];
      o1[u] = tile[row][seg * 16 + 8 + u];
    }
    short* dst = WhB2 + (size_t)(h >> 1) * NN * 128 + (size_t)(bm + row) * 128 +
                 (h & 1) * 64 + seg * 16;
    *reinterpret_cast<bf16x8*>(dst) = o0;
    *reinterpret_cast<bf16x8*>(dst + 8) = o1;
  }
}

// ---------------- K2c: strided max reduce ----------------
__global__ __launch_bounds__(256) void k_rmax(const float* __restrict__ src,
                                              float* __restrict__ dst, int n, int stride,
                                              int boff) {
  const float* p = src + (size_t)blockIdx.x * boff;
  float m = -1e30f;
  for (int k = threadIdx.x; k < n; k += 256) m = fmaxf(m, p[(size_t)k * stride]);
#pragma unroll
  for (int off = 32; off; off >>= 1) m = fmaxf(m, __shfl_xor(m, off));
  __shared__ float sm[4];
  if ((threadIdx.x & 63) == 0) sm[threadIdx.x >> 6] = m;
  __syncthreads();
  if (threadIdx.x == 0) dst[blockIdx.x] = fmaxf(fmaxf(sm[0], sm[1]), fmaxf(sm[2], sm[3]));
}

// ---------------- K3a: stream adj -> bitmask (pure HBM, nontemporal) ----------------
__global__ __launch_bounds__(256) void k_scan(const float* __restrict__ adj,
                                              unsigned int* __restrict__ bmask) {
  const fv4* a4 = reinterpret_cast<const fv4*>(adj);
  const int t0 = blockIdx.x * 256 + threadIdx.x;
#pragma unroll 4
  for (int it = 0; it < 32; ++it) {
    const int g = it * 524288 + t0;
    const fv4 v = __builtin_nontemporal_load(a4 + g);
    unsigned int nv = (unsigned int)((v.x > 0.f) | ((v.y > 0.f) << 1) |
                                     ((v.z > 0.f) << 2) | ((v.w > 0.f) << 3))
                      << ((threadIdx.x & 7) * 4);
    nv |= __shfl_xor(nv, 1);
    nv |= __shfl_xor(nv, 2);
    nv |= __shfl_xor(nv, 4);
    if ((threadIdx.x & 7) == 0) bmask[g >> 3] = nv;
  }
}

// ---------------- K3b: layer-1 attention, head-pair split (gridDim.y = 2) ----------------
__global__ __launch_bounds__(256) void k_attn1h(const unsigned int* __restrict__ bmask,
                                                const short* __restrict__ WhB2,
                                                const float* __restrict__ f1i,
                                                const float* __restrict__ f2i,
                                                const float* __restrict__ f2max,
                                                short* __restrict__ hcat) {
  __shared__ unsigned short idx[CAP];
  __shared__ unsigned int widx[2][CAP + 32];   // packed (bf16(w)<<16 | j), per local head
  __shared__ float red[4][64];
  __shared__ float swred[4][2];
  __shared__ float sinv[2];
  __shared__ int cnt;
  const int i = blockIdx.x;
  const int p = blockIdx.y;                    // head pair: heads 2p, 2p+1
  const int tid = threadIdx.x;
  const int wv = tid >> 6, lane = tid & 63;
  if (tid == 0) cnt = 0;
  __syncthreads();

  // phase A: recompact from bitmask
  {
    unsigned int word = bmask[(size_t)i * 256 + tid];
    const int c = __popc(word);
    if (c) {
      int base = atomicAdd(&cnt, c);
      const int j0 = tid * 32;
      while (word) {
        const int b = __ffs(word) - 1;
        word &= word - 1;
        if (base < CAP) idx[base++] = (unsigned short)(j0 + b);
      }
    }
  }
  __syncthreads();
  const int n = min(cnt, CAP);

  // zero-pad so phase C needs no guards
  if (tid < 64) widx[tid >> 5][n + (tid & 31)] = 0;

  // phase B: weights for the 2 local heads
  const float f1r0 = f1i[(size_t)i * 4 + p * 2];
  const float f1r1 = f1i[(size_t)i * 4 + p * 2 + 1];
  const float mrow0 = lrelu(f1r0 + f2max[p * 2]);
  const float mrow1 = lrelu(f1r1 + f2max[p * 2 + 1]);
  float sw0 = 0.f, sw1 = 0.f;
  for (int k = tid; k < n; k += 256) {
    const int j = idx[k];
    const float2 f = *reinterpret_cast<const float2*>(f2i + (size_t)j * 4 + p * 2);
    const float w0 = __expf(lrelu(f1r0 + f.x) - mrow0);
    const float w1 = __expf(lrelu(f1r1 + f.y) - mrow1);
    widx[0][k] = ((unsigned int)(unsigned short)f2b(w0) << 16) | (unsigned int)j;
    widx[1][k] = ((unsigned int)(unsigned short)f2b(w1) << 16) | (unsigned int)j;
    sw0 += w0; sw1 += w1;
  }
#pragma unroll
  for (int off = 32; off; off >>= 1) { sw0 += __shfl_xor(sw0, off); sw1 += __shfl_xor(sw1, off); }
  if (lane == 0) { swred[wv][0] = sw0; swred[wv][1] = sw1; }
  __syncthreads();
  if (tid < 2) sinv[tid] = 1.f / (swred[0][tid] + swred[1][tid] + swred[2][tid] + swred[3][tid]);

  // phase C: waves 0,1 -> local head 0; waves 2,3 -> local head 1; halves interleave
  const int hl = wv >> 1, half = wv & 1;
  const int grp = lane >> 4, l = lane & 15;
  float acc0 = 0.f, acc1 = 0.f, acc2 = 0.f, acc3 = 0.f;
  const short* wb = WhB2 + (size_t)p * NN * 128 + hl * 64 + l * 4;
  const unsigned int* wrow = widx[hl];
  __syncthreads();
  for (int kb = (half * 4 + grp) * 8; kb < n; kb += 64) {
    const uint4 pa = *reinterpret_cast<const uint4*>(wrow + kb);
    const uint4 pb = *reinterpret_cast<const uint4*>(wrow + kb + 4);
    const uint2 e0 = *reinterpret_cast<const uint2*>(wb + (size_t)(pa.x & 0xffffu) * 128);
    const uint2 e1 = *reinterpret_cast<const uint2*>(wb + (size_t)(pa.y & 0xffffu) * 128);
    const uint2 e2 = *reinterpret_cast<const uint2*>(wb + (size_t)(pa.z & 0xffffu) * 128);
    const uint2 e3 = *reinterpret_cast<const uint2*>(wb + (size_t)(pa.w & 0xffffu) * 128);
    const uint2 e4 = *reinterpret_cast<const uint2*>(wb + (size_t)(pb.x & 0xffffu) * 128);
    const uint2 e5 = *reinterpret_cast<const uint2*>(wb + (size_t)(pb.y & 0xffffu) * 128);
    const uint2 e6 = *reinterpret_cast<const uint2*>(wb + (size_t)(pb.z & 0xffffu) * 128);
    const uint2 e7 = *reinterpret_cast<const uint2*>(wb + (size_t)(pb.w & 0xffffu) * 128);
    const float w0 = __uint_as_float(pa.x & 0xffff0000u);
    const float w1 = __uint_as_float(pa.y & 0xffff0000u);
    const float w2 = __uint_as_float(pa.z & 0xffff0000u);
    const float w3 = __uint_as_float(pa.w & 0xffff0000u);
    const float w4 = __uint_as_float(pb.x & 0xffff0000u);
    const float w5 = __uint_as_float(pb.y & 0xffff0000u);
    const float w6 = __uint_as_float(pb.z & 0xffff0000u);
    const float w7 = __uint_as_float(pb.w & 0xffff0000u);
    UPF(w0, e0.x, acc0, acc1) UPF(w0, e0.y, acc2, acc3)
    UPF(w1, e1.x, acc0, acc1) UPF(w1, e1.y, acc2, acc3)
    UPF(w2, e2.x, acc0, acc1) UPF(w2, e2.y, acc2, acc3)
    UPF(w3, e3.x, acc0, acc1) UPF(w3, e3.y, acc2, acc3)
    UPF(w4, e4.x, acc0, acc1) UPF(w4, e4.y, acc2, acc3)
    UPF(w5, e5.x, acc0, acc1) UPF(w5, e5.y, acc2, acc3)
    UPF(w6, e6.x, acc0, acc1) UPF(w6, e6.y, acc2, acc3)
    UPF(w7, e7.x, acc0, acc1) UPF(w7, e7.y, acc2, acc3)
  }
  acc0 += __shfl_xor(acc0, 16); acc0 += __shfl_xor(acc0, 32);
  acc1 += __shfl_xor(acc1, 16); acc1 += __shfl_xor(acc1, 32);
  acc2 += __shfl_xor(acc2, 16); acc2 += __shfl_xor(acc2, 32);
  acc3 += __shfl_xor(acc3, 16); acc3 += __shfl_xor(acc3, 32);
  if (lane < 16) {
    red[wv][l * 4 + 0] = acc0;
    red[wv][l * 4 + 1] = acc1;
    red[wv][l * 4 + 2] = acc2;
    red[wv][l * 4 + 3] = acc3;
  }
  __syncthreads();
  if (tid < 128) {
    const int sub = tid >> 6, d = tid & 63;
    const float s = red[sub * 2][d] + red[sub * 2 + 1][d];
    hcat[(size_t)i * 256 + p * 128 + sub * 64 + d] = f2b(elu(s * sinv[sub]));
  }
}

// ---------------- K4: Wh2B = (hcat @ W_out) bf16 ; f1o/f2o ----------------
__global__ __launch_bounds__(256) void k_gemm2(const short* __restrict__ hcat,
                                               const float* __restrict__ Wout,
                                               const float* __restrict__ aout,
                                               short* __restrict__ Wh2B,
                                               float* __restrict__ f1o,
                                               float* __restrict__ f2o) {
  __shared__ float sW[NHEAD * NHID][NCLASS + 1];
  __shared__ float sh[16][NHEAD * NHID + 1];
  const int tid = threadIdx.x;
  const int r = tid >> 4, c = tid & 15;
  const int row = blockIdx.x * 16 + r;
  for (int u = tid; u < 256 * 16; u += 256) sW[u >> 4][u & 15] = Wout[u];
  for (int u = tid; u < 16 * 256; u += 256)
    sh[u >> 8][u & 255] = b2f(hcat[(size_t)(blockIdx.x * 16 + (u >> 8)) * 256 + (u & 255)]);
  __syncthreads();
  float acc = 0.f;
#pragma unroll 8
  for (int f = 0; f < 256; ++f) acc += sh[r][f] * sW[f][c];
  Wh2B[(size_t)row * NCLASS + c] = f2b(acc);
  float s1 = acc * aout[c];
  float s2 = acc * aout[NCLASS + c];
#pragma unroll
  for (int off = 8; off; off >>= 1) { s1 += __shfl_xor(s1, off); s2 += __shfl_xor(s2, off); }
  if (c == 0) { f1o[row] = s1; f2o[row] = s2; }
}

// ---------------- K5: layer-2 attention from bitmask + log_softmax ----------------
__global__ __launch_bounds__(256) void k_attn2(const unsigned int* __restrict__ bmask,
                                               const short* __restrict__ Wh2B,
                                               const float* __restrict__ f1o,
                                               const float* __restrict__ f2o,
                                               const float* __restrict__ f2omax,
                                               float* __restrict__ out) {
  __shared__ unsigned short idx[CAP];
  __shared__ unsigned int wj[CAP + 4];
  __shared__ float red[4][NCLASS];
  __shared__ float swp[4];
  __shared__ float sinvs;
  __shared__ int cnt;
  const int i = blockIdx.x;
  const int tid = threadIdx.x;
  const int wv = tid >> 6, lane = tid & 63;
  if (tid == 0) cnt = 0;
  __syncthreads();

  {
    unsigned int word = bmask[(size_t)i * 256 + tid];
    const int c = __popc(word);
    if (c) {
      int base = atomicAdd(&cnt, c);
      const int j0 = tid * 32;
      while (word) {
        const int b = __ffs(word) - 1;
        word &= word - 1;
        if (base < CAP) idx[base++] = (unsigned short)(j0 + b);
      }
    }
  }
  __syncthreads();
  const int n = min(cnt, CAP);
  if (tid < 4) wj[n + tid] = 0;

  const float f1r = f1o[i];
  const float mrow = lrelu(f1r + f2omax[0]);
  float sw = 0.f;
  for (int k = tid; k < n; k += 256) {
    const int j = idx[k];
    const float w = __expf(lrelu(f1r + f2o[j]) - mrow);
    wj[k] = ((unsigned int)(unsigned short)f2b(w) << 16) | (unsigned int)j;
    sw += w;
  }
#pragma unroll
  for (int off = 32; off; off >>= 1) sw += __shfl_xor(sw, off);
  if (lane == 0) swp[wv] = sw;
  __syncthreads();
  if (tid == 0) sinvs = 1.f / (swp[0] + swp[1] + swp[2] + swp[3]);
  __syncthreads();

  const int grp = tid >> 2, gl = tid & 3;
  float acc0 = 0.f, acc1 = 0.f, acc2 = 0.f, acc3 = 0.f;
  const short* wb = Wh2B + gl * 4;
  for (int kb = grp * 4; kb < n; kb += 256) {
    const uint4 pw = *reinterpret_cast<const uint4*>(wj + kb);
    const uint2 e0 = *reinterpret_cast<const uint2*>(wb + (size_t)(pw.x & 0xffffu) * NCLASS);
    const uint2 e1 = *reinterpret_cast<const uint2*>(wb + (size_t)(pw.y & 0xffffu) * NCLASS);
    const uint2 e2 = *reinterpret_cast<const uint2*>(wb + (size_t)(pw.z & 0xffffu) * NCLASS);
    const uint2 e3 = *reinterpret_cast<const uint2*>(wb + (size_t)(pw.w & 0xffffu) * NCLASS);
    const float w0 = __uint_as_float(pw.x & 0xffff0000u);
    const float w1 = __uint_as_float(pw.y & 0xffff0000u);
    const float w2 = __uint_as_float(pw.z & 0xffff0000u);
    const float w3 = __uint_as_float(pw.w & 0xffff0000u);
    UPF(w0, e0.x, acc0, acc1) UPF(w0, e0.y, acc2, acc3)
    UPF(w1, e1.x, acc0, acc1) UPF(w1, e1.y, acc2, acc3)
    UPF(w2, e2.x, acc0, acc1) UPF(w2, e2.y, acc2, acc3)
    UPF(w3, e3.x, acc0, acc1) UPF(w3, e3.y, acc2, acc3)
  }
  acc0 += __shfl_xor(acc0, 4);  acc1 += __shfl_xor(acc1, 4);
  acc2 += __shfl_xor(acc2, 4);  acc3 += __shfl_xor(acc3, 4);
  acc0 += __shfl_xor(acc0, 8);  acc1 += __shfl_xor(acc1, 8);
  acc2 += __shfl_xor(acc2, 8);  acc3 += __shfl_xor(acc3, 8);
  acc0 += __shfl_xor(acc0, 16); acc1 += __shfl_xor(acc1, 16);
  acc2 += __shfl_xor(acc2, 16); acc3 += __shfl_xor(acc3, 16);
  acc0 += __shfl_xor(acc0, 32); acc1 += __shfl_xor(acc1, 32);
  acc2 += __shfl_xor(acc2, 32); acc3 += __shfl_xor(acc3, 32);
  if (lane < 4) {
    red[wv][lane * 4 + 0] = acc0;
    red[wv][lane * 4 + 1] = acc1;
    red[wv][lane * 4 + 2] = acc2;
    red[wv][lane * 4 + 3] = acc3;
  }
  __syncthreads();
  if (tid < NCLASS) {
    const float s = red[0][tid] + red[1][tid] + red[2][tid] + red[3][tid];
    const float v = elu(s * sinvs);
    float vm = v;
#pragma unroll
    for (int off = 8; off; off >>= 1) vm = fmaxf(vm, __shfl_xor(vm, off, 16));
    float ex = __expf(v - vm);
#pragma unroll
    for (int off = 8; off; off >>= 1) ex += __shfl_xor(ex, off, 16);
    out[(size_t)i * NCLASS + tid] = v - vm - __logf(ex);
  }
}

extern "C" void kernel_launch(void* const* d_in, const int* in_sizes, int n_in,
                              void* d_out, int out_size, void* d_ws, size_t ws_size,
                              hipStream_t stream) {
  const float* x    = (const float*)d_in[0];
  const float* adj  = (const float*)d_in[1];
  const float* W    = (const float*)d_in[2];
  const float* a    = (const float*)d_in[3];
  const float* Wout = (const float*)d_in[4];
  const float* aout = (const float*)d_in[5];
  float* out = (float*)d_out;
  char* ws = (char*)d_ws;
  const size_t MB = 1048576;

  unsigned int* bmask  = (unsigned int*)(ws);              //  8 MB
  short* WhB2          = (short*)(ws + 8 * MB);            //  4 MB (2 x 2MB tables)
  short* hcat          = (short*)(ws + 12 * MB);           //  4 MB
  short* WB            = (short*)(ws + 16 * MB);           // 256 KB
  float* f1i           = (float*)(ws + 16 * MB + 262144);  // 128 KB
  float* f2i           = (float*)(ws + 16 * MB + 393216);  // 128 KB
  float* f1o           = (float*)(ws + 16 * MB + 524288);  //  32 KB
  float* f2o           = (float*)(ws + 16 * MB + 557056);  //  32 KB
  short* Wh2B          = (short*)(ws + 16 * MB + 589824);  // 256 KB
  float* f2max         = (float*)(ws + 16 * MB + 851968);  //  16 B
  float* f2omax        = (float*)(ws + 16 * MB + 852032);  //   4 B

  k_wprep<<<dim3(8, 4), 256, 0, stream>>>(W, WB);
  k_prep1<<<512, 256, 0, stream>>>(x, WB, a, WhB2, f1i, f2i);
  k_rmax<<<NHEAD, 256, 0, stream>>>(f2i, f2max, NN, 4, 1);
  k_scan<<<2048, 256, 0, stream>>>(adj, bmask);
  k_attn1h<<<dim3(NN, 2), 256, 0, stream>>>(bmask, WhB2, f1i, f2i, f2max, hcat);
  k_gemm2<<<NN / 16, 256, 0, stream>>>(hcat, Wout, aout, Wh2B, f1o, f2o);
  k_rmax<<<1, 256, 0, stream>>>(f2o, f2omax, NN, 1, 0);
  k_attn2<<<NN, 256, 0, stream>>>(bmask, Wh2B, f1o, f2o, f2omax, out);
}

// Round 12
// 221.900 us; speedup vs baseline: 1.1140x; 1.1140x over previous
//
#include <hip/hip_runtime.h>
#include <hip/hip_bf16.h>

#define NN 8192
#define NFEAT 512
#define NHID 64
#define NCLASS 16
#define NHEAD 4
#define ALPHA 0.1f
#define CAP 768

typedef short bf16x8 __attribute__((ext_vector_type(8)));
typedef float f32x4 __attribute__((ext_vector_type(4)));
typedef float fv4 __attribute__((ext_vector_type(4)));

__device__ __forceinline__ float lrelu(float x) { return fmaxf(x, ALPHA * x); }
__device__ __forceinline__ float elu(float x) { return x > 0.f ? x : __expf(x) - 1.f; }
__device__ __forceinline__ short f2b(float x) {
  union { __bf16 b; short s; } c; c.b = (__bf16)x; return c.s;
}
__device__ __forceinline__ float b2f(short x) {
  union { unsigned int u; float f; } c; c.u = ((unsigned int)(unsigned short)x) << 16; return c.f;
}

#define UPF(w, v, A0, A1)                                  \
  {                                                        \
    const float lo_ = __uint_as_float((v) << 16);          \
    const float hi_ = __uint_as_float((v) & 0xffff0000u);  \
    (A0) += (w) * lo_;                                     \
    (A1) += (w) * hi_;                                     \
  }

// ---------------- K0b: WB[h][d][k] = bf16(W[h][k][d]) ----------------
__global__ __launch_bounds__(256) void k_wprep(const float* __restrict__ W,
                                               short* __restrict__ WB) {
  __shared__ float t[64][65];
  const int h = blockIdx.y;
  const int k0 = blockIdx.x * 64;
  const int tid = threadIdx.x;
#pragma unroll
  for (int it = 0; it < 16; ++it) {
    const int r = it * 4 + (tid >> 6), c = tid & 63;
    t[r][c] = W[((size_t)h * NFEAT + k0 + r) * NHID + c];
  }
  __syncthreads();
#pragma unroll
  for (int it = 0; it < 16; ++it) {
    const int d = it * 4 + (tid >> 6), k = tid & 63;
    WB[((size_t)h * NHID + d) * NFEAT + k0 + k] = f2b(t[k][d]);
  }
}

// ---------------- K1: Wh = bf16(x) @ WB^T (MFMA); epilogue f1/f2 + Whf j-blocked ------
// Whf layout: [(h*1024 + j/8)*64 + d]*8 + (j&7)  — B-fragment reads fully coalesced.
__global__ __launch_bounds__(256) void k_prep1(const float* __restrict__ x,
                                               const short* __restrict__ WB,
                                               const float* __restrict__ a,
                                               short* __restrict__ Whf,
                                               float* __restrict__ f1i,
                                               float* __restrict__ f2i) {
  __shared__ short tile[64][72];
  const int bid = blockIdx.x;
  const int h = bid >> 7;
  const int bm = (bid & 127) * 64;
  const int tid = threadIdx.x;
  const int wv = tid >> 6, lane = tid & 63;
  const int mr = lane & 15, kg = lane >> 4;
  f32x4 acc0 = {0.f, 0.f, 0.f, 0.f}, acc1 = acc0, acc2 = acc0, acc3 = acc0;
  const float* ap = x + (size_t)(bm + wv * 16 + mr) * NFEAT + kg * 8;
  const short* bp = WB + ((size_t)h * NHID + mr) * NFEAT + kg * 8;
#pragma unroll 2
  for (int k0 = 0; k0 < NFEAT; k0 += 32) {
    const float4 xa = *reinterpret_cast<const float4*>(ap);
    const float4 xb = *reinterpret_cast<const float4*>(ap + 4);
    bf16x8 af;
    af[0] = f2b(xa.x); af[1] = f2b(xa.y); af[2] = f2b(xa.z); af[3] = f2b(xa.w);
    af[4] = f2b(xb.x); af[5] = f2b(xb.y); af[6] = f2b(xb.z); af[7] = f2b(xb.w);
    const bf16x8 b0 = *reinterpret_cast<const bf16x8*>(bp);
    const bf16x8 b1 = *reinterpret_cast<const bf16x8*>(bp + 16 * NFEAT);
    const bf16x8 b2 = *reinterpret_cast<const bf16x8*>(bp + 32 * NFEAT);
    const bf16x8 b3 = *reinterpret_cast<const bf16x8*>(bp + 48 * NFEAT);
    acc0 = __builtin_amdgcn_mfma_f32_16x16x32_bf16(af, b0, acc0, 0, 0, 0);
    acc1 = __builtin_amdgcn_mfma_f32_16x16x32_bf16(af, b1, acc1, 0, 0, 0);
    acc2 = __builtin_amdgcn_mfma_f32_16x16x32_bf16(af, b2, acc2, 0, 0, 0);
    acc3 = __builtin_amdgcn_mfma_f32_16x16x32_bf16(af, b3, acc3, 0, 0, 0);
    ap += 32; bp += 32;
  }
  float a1v[4], a2v[4];
#pragma unroll
  for (int c = 0; c < 4; ++c) {
    a1v[c] = a[h * 128 + mr + c * 16];
    a2v[c] = a[h * 128 + 64 + mr + c * 16];
  }
#pragma unroll
  for (int q = 0; q < 4; ++q) {
    float s1 = acc0[q] * a1v[0] + acc1[q] * a1v[1] + acc2[q] * a1v[2] + acc3[q] * a1v[3];
    float s2 = acc0[q] * a2v[0] + acc1[q] * a2v[1] + acc2[q] * a2v[2] + acc3[q] * a2v[3];
#pragma unroll
    for (int off = 1; off < 16; off <<= 1) {
      s1 += __shfl_xor(s1, off);
      s2 += __shfl_xor(s2, off);
    }
    if (mr == 0) {
      const int i = bm + wv * 16 + kg * 4 + q;
      f1i[(size_t)i * 4 + h] = s1;
      f2i[(size_t)i * 4 + h] = s2;
    }
  }
#pragma unroll
  for (int q = 0; q < 4; ++q) {
    const int r = wv * 16 + kg * 4 + q;
    tile[r][mr +  0] = f2b(acc0[q]);
    tile[r][mr + 16] = f2b(acc1[q]);
    tile[r][mr + 32] = f2b(acc2[q]);
    tile[r][mr + 48] = f2b(acc3[q]);
  }
  __syncthreads();
#pragma unroll
  for (int it = 0; it < 2; ++it) {
    const int jbl = (tid >> 6) + it * 4;   // 0..7 local j-block
    const int d = tid & 63;
    bf16x8 o;
#pragma unroll
    for (int jo = 0; jo < 8; ++jo) o[jo] = tile[jbl * 8 + jo][d];
    *reinterpret_cast<bf16x8*>(Whf +
        (((size_t)h * 1024 + (bm >> 3) + jbl) * 64 + d) * 8) = o;
  }
}

// ---------------- K2c: strided max reduce ----------------
__global__ __launch_bounds__(256) void k_rmax(const float* __restrict__ src,
                                              float* __restrict__ dst, int n, int stride,
                                              int boff) {
  const float* p = src + (size_t)blockIdx.x * boff;
  float m = -1e30f;
  for (int k = threadIdx.x; k < n; k += 256) m = fmaxf(m, p[(size_t)k * stride]);
#pragma unroll
  for (int off = 32; off; off >>= 1) m = fmaxf(m, __shfl_xor(m, off));
  __shared__ float sm[4];
  if ((threadIdx.x & 63) == 0) sm[threadIdx.x >> 6] = m;
  __syncthreads();
  if (threadIdx.x == 0) dst[blockIdx.x] = fmaxf(fmaxf(sm[0], sm[1]), fmaxf(sm[2], sm[3]));
}

// ---------------- K2d: per-node factor tables ----------------
// A=e^{f1+f2max-mrow}, C=e^{0.1(f1+f2max)-mrow} (f32); B=e^{f2-f2max}, D=e^{0.1(f2-f2max)} (bf16 packed)
__global__ __launch_bounds__(256) void k_acbd(const float* __restrict__ f1i,
                                              const float* __restrict__ f2i,
                                              const float* __restrict__ f2max,
                                              float2* __restrict__ ACh,
                                              unsigned int* __restrict__ BDh) {
  const int idx = blockIdx.x * 256 + threadIdx.x;   // 32768 = NN*NHEAD
  const int i = idx & (NN - 1);
  const int h = idx >> 13;
  const float fm = f2max[h];
  const float f1 = f1i[(size_t)i * 4 + h];
  const float f2 = f2i[(size_t)i * 4 + h];
  const float s = f1 + fm;
  const float mrow = fmaxf(s, 0.1f * s);
  float2 ac;
  ac.x = __expf(s - mrow);
  ac.y = __expf(0.1f * s - mrow);
  ACh[(size_t)h * NN + i] = ac;
  const float t = f2 - fm;
  const unsigned int B = (unsigned short)f2b(__expf(t));
  const unsigned int D = (unsigned short)f2b(__expf(0.1f * t));
  BDh[(size_t)h * NN + i] = B | (D << 16);
}

// ---------------- K3a: stream adj -> bitmask (pure HBM, nontemporal) ----------------
__global__ __launch_bounds__(256) void k_scan(const float* __restrict__ adj,
                                              unsigned int* __restrict__ bmask) {
  const fv4* a4 = reinterpret_cast<const fv4*>(adj);
  const int t0 = blockIdx.x * 256 + threadIdx.x;
#pragma unroll 4
  for (int it = 0; it < 32; ++it) {
    const int g = it * 524288 + t0;
    const fv4 v = __builtin_nontemporal_load(a4 + g);
    unsigned int nv = (unsigned int)((v.x > 0.f) | ((v.y > 0.f) << 1) |
                                     ((v.z > 0.f) << 2) | ((v.w > 0.f) << 3))
                      << ((threadIdx.x & 7) * 4);
    nv |= __shfl_xor(nv, 1);
    nv |= __shfl_xor(nv, 2);
    nv |= __shfl_xor(nv, 4);
    if ((threadIdx.x & 7) == 0) bmask[g >> 3] = nv;
  }
}

// ---------------- K3b: masked dense MFMA layer-1 attention ----------------
// grid (128, NHEAD): block = 64 rows x 1 head, 4 waves (wave = 16-row M-sub).
// w'_ij = mask * max(A_i*B_j, C_i*D_j)  -> one GEMM vs Whf, rowsum in-register.
#define DCH 512
__global__ __launch_bounds__(256) void k_dense1(const unsigned int* __restrict__ bmask,
                                                const short* __restrict__ Whf,
                                                const float2* __restrict__ ACh,
                                                const unsigned int* __restrict__ BDh,
                                                short* __restrict__ hcat) {
  __shared__ unsigned int sm_mask[64][16];   // 64 rows x 512 bits
  __shared__ unsigned int sm_bd[DCH];
  __shared__ float sm_iv[4][16];
  __shared__ short sm_out[64][72];
  const int i0 = blockIdx.x * 64;
  const int h = blockIdx.y;
  const int tid = threadIdx.x;
  const int wv = tid >> 6, lane = tid & 63;
  const int mr = lane & 15, kg = lane >> 4;
  const int row_local = wv * 16 + mr;        // A-fragment row for this lane
  const float2 ac = ACh[(size_t)h * NN + i0 + row_local];
  f32x4 acc0 = {0.f, 0.f, 0.f, 0.f}, acc1 = acc0, acc2 = acc0, acc3 = acc0;
  float rs = 0.f;
  const int rr = tid >> 2, w0 = (tid & 3) * 4;

  for (int jc = 0; jc < NN; jc += DCH) {
    __syncthreads();
    {
      const unsigned int* src = bmask + (size_t)(i0 + rr) * 256 + (jc >> 5);
#pragma unroll
      for (int u = 0; u < 4; ++u) sm_mask[rr][w0 + u] = src[w0 + u];
      sm_bd[tid] = BDh[(size_t)h * NN + jc + tid];
      sm_bd[tid + 256] = BDh[(size_t)h * NN + jc + tid + 256];
    }
    __syncthreads();
#pragma unroll 4
    for (int ks = 0; ks < DCH / 32; ++ks) {
      const int jl = ks * 32 + kg * 8;
      const uint4 bda = *reinterpret_cast<const uint4*>(&sm_bd[jl]);
      const uint4 bdb = *reinterpret_cast<const uint4*>(&sm_bd[jl + 4]);
      const unsigned int mb = (sm_mask[row_local][ks] >> (kg * 8)) & 0xffu;
      bf16x8 af;
#define MKW(e, bdw)                                              \
      {                                                          \
        const float Bf = __uint_as_float((bdw) << 16);           \
        const float Df = __uint_as_float((bdw) & 0xffff0000u);   \
        float w_ = fmaxf(ac.x * Bf, ac.y * Df);                  \
        w_ = ((mb >> (e)) & 1u) ? w_ : 0.f;                      \
        rs += w_;                                                \
        af[e] = f2b(w_);                                         \
      }
      MKW(0, bda.x) MKW(1, bda.y) MKW(2, bda.z) MKW(3, bda.w)
      MKW(4, bdb.x) MKW(5, bdb.y) MKW(6, bdb.z) MKW(7, bdb.w)
#undef MKW
      const short* wp = Whf + (((size_t)h * 1024 + ((jc + jl) >> 3)) * 64 + mr) * 8;
      const bf16x8 bf0 = *reinterpret_cast<const bf16x8*>(wp);
      const bf16x8 bf1 = *reinterpret_cast<const bf16x8*>(wp + 128);
      const bf16x8 bf2 = *reinterpret_cast<const bf16x8*>(wp + 256);
      const bf16x8 bf3 = *reinterpret_cast<const bf16x8*>(wp + 384);
      acc0 = __builtin_amdgcn_mfma_f32_16x16x32_bf16(af, bf0, acc0, 0, 0, 0);
      acc1 = __builtin_amdgcn_mfma_f32_16x16x32_bf16(af, bf1, acc1, 0, 0, 0);
      acc2 = __builtin_amdgcn_mfma_f32_16x16x32_bf16(af, bf2, acc2, 0, 0, 0);
      acc3 = __builtin_amdgcn_mfma_f32_16x16x32_bf16(af, bf3, acc3, 0, 0, 0);
    }
  }
  // rowsum: reduce over the 4 k-groups -> lanes 0..15 hold rows 0..15 of this wave
  rs += __shfl_xor(rs, 16);
  rs += __shfl_xor(rs, 32);
  if (lane < 16) sm_iv[wv][lane] = 1.f / rs;
  __syncthreads();
#pragma unroll
  for (int q = 0; q < 4; ++q) {
    const float ivq = sm_iv[wv][kg * 4 + q];
    const int r = wv * 16 + kg * 4 + q;
    sm_out[r][mr +  0] = f2b(elu(acc0[q] * ivq));
    sm_out[r][mr + 16] = f2b(elu(acc1[q] * ivq));
    sm_out[r][mr + 32] = f2b(elu(acc2[q] * ivq));
    sm_out[r][mr + 48] = f2b(elu(acc3[q] * ivq));
  }
  __syncthreads();
  {
    const int r = tid >> 2, seg = tid & 3;
    bf16x8 o;
#pragma unroll
    for (int u = 0; u < 8; ++u) o[u] = sm_out[r][seg * 16 + u];
    short* dst = hcat + (size_t)(i0 + r) * 256 + h * 64 + seg * 16;
    *reinterpret_cast<bf16x8*>(dst) = o;
    bf16x8 o2;
#pragma unroll
    for (int u = 0; u < 8; ++u) o2[u] = sm_out[r][seg * 16 + 8 + u];
    *reinterpret_cast<bf16x8*>(dst + 8) = o2;
  }
}

// ---------------- K4: Wh2B = (hcat @ W_out) bf16 ; f1o/f2o ----------------
__global__ __launch_bounds__(256) void k_gemm2(const short* __restrict__ hcat,
                                               const float* __restrict__ Wout,
                                               const float* __restrict__ aout,
                                               short* __restrict__ Wh2B,
                                               float* __restrict__ f1o,
                                               float* __restrict__ f2o) {
  __shared__ float sW[NHEAD * NHID][NCLASS + 1];
  __shared__ float sh[16][NHEAD * NHID + 1];
  const int tid = threadIdx.x;
  const int r = tid >> 4, c = tid & 15;
  const int row = blockIdx.x * 16 + r;
  for (int u = tid; u < 256 * 16; u += 256) sW[u >> 4][u & 15] = Wout[u];
  for (int u = tid; u < 16 * 256; u += 256)
    sh[u >> 8][u & 255] = b2f(hcat[(size_t)(blockIdx.x * 16 + (u >> 8)) * 256 + (u & 255)]);
  __syncthreads();
  float acc = 0.f;
#pragma unroll 8
  for (int f = 0; f < 256; ++f) acc += sh[r][f] * sW[f][c];
  Wh2B[(size_t)row * NCLASS + c] = f2b(acc);
  float s1 = acc * aout[c];
  float s2 = acc * aout[NCLASS + c];
#pragma unroll
  for (int off = 8; off; off >>= 1) { s1 += __shfl_xor(s1, off); s2 += __shfl_xor(s2, off); }
  if (c == 0) { f1o[row] = s1; f2o[row] = s2; }
}

// ---------------- K5: layer-2 attention from bitmask + log_softmax ----------------
__global__ __launch_bounds__(256) void k_attn2(const unsigned int* __restrict__ bmask,
                                               const short* __restrict__ Wh2B,
                                               const float* __restrict__ f1o,
                                               const float* __restrict__ f2o,
                                               const float* __restrict__ f2omax,
                                               float* __restrict__ out) {
  __shared__ unsigned short idx[CAP];
  __shared__ unsigned int wj[CAP + 4];
  __shared__ float red[4][NCLASS];
  __shared__ float swp[4];
  __shared__ float sinvs;
  __shared__ int cnt;
  const int i = blockIdx.x;
  const int tid = threadIdx.x;
  const int wv = tid >> 6, lane = tid & 63;
  if (tid == 0) cnt = 0;
  __syncthreads();

  {
    unsigned int word = bmask[(size_t)i * 256 + tid];
    const int c = __popc(word);
    if (c) {
      int base = atomicAdd(&cnt, c);
      const int j0 = tid * 32;
      while (word) {
        const int b = __ffs(word) - 1;
        word &= word - 1;
        if (base < CAP) idx[base++] = (unsigned short)(j0 + b);
      }
    }
  }
  __syncthreads();
  const int n = min(cnt, CAP);
  if (tid < 4) wj[n + tid] = 0;

  const float f1r = f1o[i];
  const float mrow = lrelu(f1r + f2omax[0]);
  float sw = 0.f;
  for (int k = tid; k < n; k += 256) {
    const int j = idx[k];
    const float w = __expf(lrelu(f1r + f2o[j]) - mrow);
    wj[k] = ((unsigned int)(unsigned short)f2b(w) << 16) | (unsigned int)j;
    sw += w;
  }
#pragma unroll
  for (int off = 32; off; off >>= 1) sw += __shfl_xor(sw, off);
  if (lane == 0) swp[wv] = sw;
  __syncthreads();
  if (tid == 0) sinvs = 1.f / (swp[0] + swp[1] + swp[2] + swp[3]);
  __syncthreads();

  const int grp = tid >> 2, gl = tid & 3;
  float acc0 = 0.f, acc1 = 0.f, acc2 = 0.f, acc3 = 0.f;
  const short* wb = Wh2B + gl * 4;
  for (int kb = grp * 4; kb < n; kb += 256) {
    const uint4 pw = *reinterpret_cast<const uint4*>(wj + kb);
    const uint2 e0 = *reinterpret_cast<const uint2*>(wb + (size_t)(pw.x & 0xffffu) * NCLASS);
    const uint2 e1 = *reinterpret_cast<const uint2*>(wb + (size_t)(pw.y & 0xffffu) * NCLASS);
    const uint2 e2 = *reinterpret_cast<const uint2*>(wb + (size_t)(pw.z & 0xffffu) * NCLASS);
    const uint2 e3 = *reinterpret_cast<const uint2*>(wb + (size_t)(pw.w & 0xffffu) * NCLASS);
    const float w0 = __uint_as_float(pw.x & 0xffff0000u);
    const float w1 = __uint_as_float(pw.y & 0xffff0000u);
    const float w2 = __uint_as_float(pw.z & 0xffff0000u);
    const float w3 = __uint_as_float(pw.w & 0xffff0000u);
    UPF(w0, e0.x, acc0, acc1) UPF(w0, e0.y, acc2, acc3)
    UPF(w1, e1.x, acc0, acc1) UPF(w1, e1.y, acc2, acc3)
    UPF(w2, e2.x, acc0, acc1) UPF(w2, e2.y, acc2, acc3)
    UPF(w3, e3.x, acc0, acc1) UPF(w3, e3.y, acc2, acc3)
  }
  acc0 += __shfl_xor(acc0, 4);  acc1 += __shfl_xor(acc1, 4);
  acc2 += __shfl_xor(acc2, 4);  acc3 += __shfl_xor(acc3, 4);
  acc0 += __shfl_xor(acc0, 8);  acc1 += __shfl_xor(acc1, 8);
  acc2 += __shfl_xor(acc2, 8);  acc3 += __shfl_xor(acc3, 8);
  acc0 += __shfl_xor(acc0, 16); acc1 += __shfl_xor(acc1, 16);
  acc2 += __shfl_xor(acc2, 16); acc3 += __shfl_xor(acc3, 16);
  acc0 += __shfl_xor(acc0, 32); acc1 += __shfl_xor(acc1, 32);
  acc2 += __shfl_xor(acc2, 32); acc3 += __shfl_xor(acc3, 32);
  if (lane < 4) {
    red[wv][lane * 4 + 0] = acc0;
    red[wv][lane * 4 + 1] = acc1;
    red[wv][lane * 4 + 2] = acc2;
    red[wv][lane * 4 + 3] = acc3;
  }
  __syncthreads();
  if (tid < NCLASS) {
    const float s = red[0][tid] + red[1][tid] + red[2][tid] + red[3][tid];
    const float v = elu(s * sinvs);
    float vm = v;
#pragma unroll
    for (int off = 8; off; off >>= 1) vm = fmaxf(vm, __shfl_xor(vm, off, 16));
    float ex = __expf(v - vm);
#pragma unroll
    for (int off = 8; off; off >>= 1) ex += __shfl_xor(ex, off, 16);
    out[(size_t)i * NCLASS + tid] = v - vm - __logf(ex);
  }
}

extern "C" void kernel_launch(void* const* d_in, const int* in_sizes, int n_in,
                              void* d_out, int out_size, void* d_ws, size_t ws_size,
                              hipStream_t stream) {
  const float* x    = (const float*)d_in[0];
  const float* adj  = (const float*)d_in[1];
  const float* W    = (const float*)d_in[2];
  const float* a    = (const float*)d_in[3];
  const float* Wout = (const float*)d_in[4];
  const float* aout = (const float*)d_in[5];
  float* out = (float*)d_out;
  char* ws = (char*)d_ws;
  const size_t MB = 1048576;
  const size_t KB = 1024;

  unsigned int* bmask  = (unsigned int*)(ws);                    //  8 MB
  short* Whf           = (short*)(ws + 8 * MB);                  //  4 MB
  short* hcat          = (short*)(ws + 12 * MB);                 //  4 MB
  short* WB            = (short*)(ws + 16 * MB);                 // 256 KB
  float* f1i           = (float*)(ws + 16 * MB + 256 * KB);      // 128 KB
  float* f2i           = (float*)(ws + 16 * MB + 384 * KB);      // 128 KB
  float2* ACh          = (float2*)(ws + 16 * MB + 512 * KB);     // 256 KB
  unsigned int* BDh    = (unsigned int*)(ws + 16 * MB + 768 * KB); // 128 KB
  float* f1o           = (float*)(ws + 16 * MB + 896 * KB);      //  32 KB
  float* f2o           = (float*)(ws + 16 * MB + 928 * KB);      //  32 KB
  short* Wh2B          = (short*)(ws + 16 * MB + 960 * KB);      // 256 KB
  float* f2max         = (float*)(ws + 16 * MB + 1216 * KB);     //  16 B
  float* f2omax        = (float*)(ws + 16 * MB + 1216 * KB + 64);

  k_wprep<<<dim3(8, 4), 256, 0, stream>>>(W, WB);
  k_prep1<<<512, 256, 0, stream>>>(x, WB, a, Whf, f1i, f2i);
  k_rmax<<<NHEAD, 256, 0, stream>>>(f2i, f2max, NN, 4, 1);
  k_acbd<<<NN * NHEAD / 256, 256, 0, stream>>>(f1i, f2i, f2max, ACh, BDh);
  k_scan<<<2048, 256, 0, stream>>>(adj, bmask);
  k_dense1<<<dim3(NN / 64, NHEAD), 256, 0, stream>>>(bmask, Whf, ACh, BDh, hcat);
  k_gemm2<<<NN / 16, 256, 0, stream>>>(hcat, Wout, aout, Wh2B, f1o, f2o);
  k_rmax<<<1, 256, 0, stream>>>(f2o, f2omax, NN, 1, 0);
  k_attn2<<<NN, 256, 0, stream>>>(bmask, Wh2B, f1o, f2o, f2omax, out);
}